// Round 13
// baseline (600.577 us; speedup 1.0000x reference)
//
#include <hip/hip_runtime.h>

#define DEV __device__ __forceinline__

typedef __bf16 bf16x8 __attribute__((ext_vector_type(8)));
typedef float  f32x4  __attribute__((ext_vector_type(4)));

// ---------- helpers ----------
DEV unsigned short f2b(float f) {                 // f32 -> bf16 (RNE)
    union { float f; unsigned u; } v; v.f = f;
    unsigned r = v.u + 0x7fffu + ((v.u >> 16) & 1u);
    return (unsigned short)(r >> 16);
}
DEV float b2f(unsigned short h) {
    union { unsigned u; float f; } v; v.u = ((unsigned)h) << 16;
    return v.f;
}
DEV float sigmoidf_(float x) { return 1.f / (1.f + __expf(-x)); }
DEV float geluf_(float x) {                       // jax default: tanh approximation
    float t = 0.7978845608028654f * (x + 0.044715f * x * x * x);
    return 0.5f * x * (1.f + tanhf(t));
}
DEV float softplusf_(float x) { return x > 15.f ? x : log1pf(__expf(x)); }
DEV void gload_lds16(const void* g, void* l) {
    __builtin_amdgcn_global_load_lds((const __attribute__((address_space(1))) void*)g,
                                     (__attribute__((address_space(3))) void*)l, 16, 0, 0);
}

// ---------- problem constants ----------
// B=32 L=256 D=512 D_INNER=1024 D_STATE=16 DT_RANK=32 D_FF=2048, M = B*L = 8192
// proj layout (64 cols): [dt(32) | B(16) | C(16)]

// ---------- weight transpose+convert: W (K,N) f32 -> W^T (N,K) bf16 ----------
struct WtDesc { const float* s; unsigned short* d; int K; int N; int t0; };
struct WtArgs { WtDesc m[12]; };

__global__ __launch_bounds__(256) void wtrans_k(WtArgs a) {
    __shared__ float tile[32][33];
    int t = blockIdx.x;
    int mi = 0;
#pragma unroll
    for (int j = 1; j < 12; j++) if (t >= a.m[j].t0) mi = j;
    const float* src0 = a.m[mi].s;
    unsigned short* dst0 = a.m[mi].d;
    const int K = a.m[mi].K, N = a.m[mi].N;
    const int lt = t - a.m[mi].t0;
    const int ntk = K >> 5;
    const int kt = lt % ntk, nt = lt / ntk;
    const int c = threadIdx.x & 31, r = threadIdx.x >> 5;
    const float* src = src0 + (size_t)(kt * 32) * N + nt * 32;
#pragma unroll
    for (int i = 0; i < 4; i++) tile[r + i * 8][c] = src[(size_t)(r + i * 8) * N + c];
    __syncthreads();
    unsigned short* dst = dst0 + (size_t)(nt * 32) * K + kt * 32;
#pragma unroll
    for (int i = 0; i < 4; i++) dst[(size_t)(r + i * 8) * K + c] = f2b(tile[c][r + i * 8]);
}

// ---------- xd = causal diff of x, emitted bf16 (4 elems/thread) ----------
__global__ __launch_bounds__(256) void diff_k(const float* __restrict__ x,
                                              unsigned short* __restrict__ xd) {
    size_t i4 = (size_t)blockIdx.x * 256 + threadIdx.x;
    size_t idx = i4 * 4;
    int l = (int)((idx >> 9) & 255);
    float4 v = *(const float4*)&x[idx];
    if (l > 0) {
        float4 p = *(const float4*)&x[idx - 512];
        v.x -= p.x; v.y -= p.y; v.z -= p.z; v.w -= p.w;
    }
    unsigned short o[4] = {f2b(v.x), f2b(v.y), f2b(v.z), f2b(v.w)};
    *(unsigned long long*)&xd[idx] = *(unsigned long long*)o;
}

// ---------- adjacency: softmax(relu(e1 @ e2^T)) ----------
__global__ __launch_bounds__(256) void adj_k(const float* __restrict__ e1,
                                             const float* __restrict__ e2,
                                             float* __restrict__ adjf,
                                             unsigned short* __restrict__ adjb) {
    const int n = blockIdx.x, tid = threadIdx.x;
    __shared__ float e1s[16];
    __shared__ float redm[4], reds[4];
    if (tid < 16) e1s[tid] = e1[n * 16 + tid];
    __syncthreads();
    const float* e2r = e2 + tid * 16;
    float dot = 0.f;
#pragma unroll
    for (int k = 0; k < 16; k++) dot = fmaf(e1s[k], e2r[k], dot);
    float v = fmaxf(dot, 0.f);
    float m = v;
#pragma unroll
    for (int o = 32; o > 0; o >>= 1) m = fmaxf(m, __shfl_xor(m, o));
    const int lane = tid & 63, wv = tid >> 6;
    if (lane == 0) redm[wv] = m;
    __syncthreads();
    m = fmaxf(fmaxf(redm[0], redm[1]), fmaxf(redm[2], redm[3]));
    float e = __expf(v - m);
    float ssum = e;
#pragma unroll
    for (int o = 32; o > 0; o >>= 1) ssum += __shfl_xor(ssum, o);
    if (lane == 0) reds[wv] = ssum;
    __syncthreads();
    ssum = reds[0] + reds[1] + reds[2] + reds[3];
    float o = e / ssum;
    adjf[(size_t)n * 256 + tid] = o;
    adjb[(size_t)n * 256 + tid] = f2b(o);
}

// ---------- 256x256 bf16 MFMA GEMM, 8 waves, dbuf 2-phase prefetch (r5-best) ----------
template<int HBIAS, int HGELU>
__global__ __launch_bounds__(512, 2) void gemm256_k(
    const unsigned short* __restrict__ A, const unsigned short* __restrict__ Bt,
    unsigned short* __restrict__ C, const float* __restrict__ bias,
    int M, int N, int K, int lda) {
    constexpr int BM = 256, BN = 256, BK = 64;
    __shared__ __align__(16) unsigned short As[2][BM * BK];
    __shared__ __align__(16) unsigned short Bs[2][BN * BK];
    const int tid  = threadIdx.x;
    const int lane = tid & 63;
    const int wave = tid >> 6;
    const int wr = wave >> 2;
    const int wc = wave & 3;
    const int bm = blockIdx.x * BM, bn = blockIdx.y * BN;
    const int lrow  = lane & 15;
    const int klane = lane >> 4;

    f32x4 acc[8][4];
#pragma unroll
    for (int m = 0; m < 8; m++)
#pragma unroll
        for (int n = 0; n < 4; n++) {
            acc[m][n][0] = 0.f; acc[m][n][1] = 0.f; acc[m][n][2] = 0.f; acc[m][n][3] = 0.f;
        }

    auto STAGE = [&](int buf, int k0) {
#pragma unroll
        for (int it = 0; it < 4; ++it) {
            int flat = (it * 512 + tid) * 8;
            int r = flat >> 6, s = (flat & 63) >> 3;
            int c = (s ^ (r & 7)) * 8;
            gload_lds16(A + (size_t)(bm + r) * lda + (k0 + c),
                        &As[buf][(it * 512 + (tid & 448)) * 8]);
        }
#pragma unroll
        for (int it = 0; it < 4; ++it) {
            int flat = (it * 512 + tid) * 8;
            int r = flat >> 6, s = (flat & 63) >> 3;
            int c = (s ^ (r & 7)) * 8;
            gload_lds16(Bt + (size_t)(bn + r) * K + (k0 + c),
                        &Bs[buf][(it * 512 + (tid & 448)) * 8]);
        }
    };
    auto COMPUTE = [&](int buf) {
#pragma unroll
        for (int kk = 0; kk < 2; kk++) {
            bf16x8 af[8], bfv[4];
#pragma unroll
            for (int m = 0; m < 8; m++) {
                int rr = wr * 128 + m * 16 + lrow;
                int sl = (kk * 4 + klane) ^ (rr & 7);
                af[m] = *(const bf16x8*)&As[buf][rr * BK + sl * 8];
            }
#pragma unroll
            for (int n = 0; n < 4; n++) {
                int rr = wc * 64 + n * 16 + lrow;
                int sl = (kk * 4 + klane) ^ (rr & 7);
                bfv[n] = *(const bf16x8*)&Bs[buf][rr * BK + sl * 8];
            }
#pragma unroll
            for (int m = 0; m < 8; m++)
#pragma unroll
                for (int n = 0; n < 4; n++)
                    acc[m][n] = __builtin_amdgcn_mfma_f32_16x16x32_bf16(af[m], bfv[n], acc[m][n], 0, 0, 0);
        }
    };

    const int nt = K / BK;
    STAGE(0, 0);
    __syncthreads();
    for (int t = 0; t < nt; t += 2) {
        if (t + 1 < nt) STAGE(1, (t + 1) * BK);
        COMPUTE(0);
        __syncthreads();
        if (t + 1 < nt) {
            if (t + 2 < nt) STAGE(0, (t + 2) * BK);
            COMPUTE(1);
            if (t + 2 < nt) __syncthreads();
        }
    }

    // staged coalesced bf16 epilogue (reuses As[0]): 8 groups of 32 rows x 256 cols
    const int r0 = (lane >> 4) << 2;
    unsigned short* Cs = As[0];
    constexpr int PITCH = BN + 8;
#pragma unroll
    for (int g = 0; g < 8; g++) {
        __syncthreads();
        if (wr == (g >> 2)) {
#pragma unroll
            for (int mm = 0; mm < 2; mm++) {
                const int m = (g & 3) * 2 + mm;
#pragma unroll
                for (int n = 0; n < 4; n++) {
                    const int cl = wc * 64 + n * 16 + lrow;
                    float bv = HBIAS ? bias[bn + cl] : 0.f;
#pragma unroll
                    for (int j = 0; j < 4; j++) {
                        float v = acc[m][n][j] + bv;
                        if (HGELU) v = geluf_(v);
                        Cs[(mm * 16 + r0 + j) * PITCH + cl] = f2b(v);
                    }
                }
            }
        }
        __syncthreads();
#pragma unroll
        for (int i = 0; i < 2; i++) {
            int flat = (i * 512 + tid) * 8;
            int row = flat >> 8, col = flat & 255;
            uint4 val = *(const uint4*)&Cs[row * PITCH + col];
            *(uint4*)&C[(size_t)(bm + g * 32 + row) * N + bn + col] = val;
        }
    }
}

// ---------- 128-class bf16 MFMA GEMM (single-buffer 2-barrier; ldb decoupled) ----------
template<int BM, int BN, int BK, int WRN, int FM, int FN,
         int OBF, int HBIAS, int HGELU, int HRES, int HSP>
__global__ __launch_bounds__(256) void gemm_k(
    const unsigned short* __restrict__ A, const unsigned short* __restrict__ Bt,
    void* __restrict__ C, const float* __restrict__ bias, const float* __restrict__ res,
    int M, int N, int K, int lda, int ldb, long sA, long sB, long sC) {
    constexpr int SMASK = BK / 8 - 1;
    constexpr int KH    = BK / 32;
    __shared__ __align__(16) unsigned short As[BM * BK];
    __shared__ __align__(16) unsigned short Bs[BN * BK];
    const int tid  = threadIdx.x;
    const int lane = tid & 63;
    const int wave = tid >> 6;
    const int wr = wave / WRN, wc = wave % WRN;
    const int bm = blockIdx.x * BM, bn = blockIdx.y * BN;
    const unsigned short* Ab = A  + (size_t)blockIdx.z * sA;
    const unsigned short* Bb = Bt + (size_t)blockIdx.z * sB;
    const int lrow  = lane & 15;
    const int klane = lane >> 4;

    f32x4 acc[FM][FN];
#pragma unroll
    for (int m = 0; m < FM; m++)
#pragma unroll
        for (int n = 0; n < FN; n++) {
            acc[m][n][0] = 0.f; acc[m][n][1] = 0.f; acc[m][n][2] = 0.f; acc[m][n][3] = 0.f;
        }

    constexpr int AI = (BM * BK) / 2048;
    constexpr int BI = (BN * BK) / 2048;

    for (int k0 = 0; k0 < K; k0 += BK) {
#pragma unroll
        for (int it = 0; it < AI; ++it) {
            int flat = (it * 256 + tid) * 8;
            int r = flat / BK, s = (flat % BK) >> 3;
            int c = (s ^ (r & SMASK)) * 8;
            gload_lds16(Ab + (size_t)(bm + r) * lda + (k0 + c),
                        &As[(it * 256 + (tid & 192)) * 8]);
        }
#pragma unroll
        for (int it = 0; it < BI; ++it) {
            int flat = (it * 256 + tid) * 8;
            int r = flat / BK, s = (flat % BK) >> 3;
            int c = (s ^ (r & SMASK)) * 8;
            gload_lds16(Bb + (size_t)(bn + r) * ldb + (k0 + c),
                        &Bs[(it * 256 + (tid & 192)) * 8]);
        }
        __syncthreads();
#pragma unroll
        for (int kk = 0; kk < KH; kk++) {
            bf16x8 af[FM], bfv[FN];
#pragma unroll
            for (int m = 0; m < FM; m++) {
                int rr = wr * FM * 16 + m * 16 + lrow;
                int sl = (kk * 4 + klane) ^ (rr & SMASK);
                af[m] = *(const bf16x8*)&As[rr * BK + sl * 8];
            }
#pragma unroll
            for (int n = 0; n < FN; n++) {
                int rr = wc * FN * 16 + n * 16 + lrow;
                int sl = (kk * 4 + klane) ^ (rr & SMASK);
                bfv[n] = *(const bf16x8*)&Bs[rr * BK + sl * 8];
            }
#pragma unroll
            for (int m = 0; m < FM; m++)
#pragma unroll
                for (int n = 0; n < FN; n++)
                    acc[m][n] = __builtin_amdgcn_mfma_f32_16x16x32_bf16(af[m], bfv[n], acc[m][n], 0, 0, 0);
        }
        __syncthreads();
    }

    const int r0 = (lane >> 4) << 2;
    if (OBF) {
        unsigned short* Cs = Bs;
        constexpr int PITCH = BN + 8;
        unsigned short* Cg = (unsigned short*)C;
#pragma unroll
        for (int g = 0; g < BM / 32; g++) {
            __syncthreads();
            if (wr == (g * 2) / FM) {
                const int mb = (g * 2) % FM;
#pragma unroll
                for (int mm = 0; mm < 2; mm++) {
#pragma unroll
                    for (int n = 0; n < FN; n++) {
                        const int cl = wc * FN * 16 + n * 16 + lrow;
                        float bv = HBIAS ? bias[bn + cl] : 0.f;
#pragma unroll
                        for (int j = 0; j < 4; j++) {
                            float v = acc[mb + mm][n][j] + bv;
                            if (HSP)   v = softplusf_(v);
                            if (HGELU) v = geluf_(v);
                            Cs[(mm * 16 + r0 + j) * PITCH + cl] = f2b(v);
                        }
                    }
                }
            }
            __syncthreads();
#pragma unroll
            for (int i = 0; i < (32 * BN) / 2048; i++) {
                int flat = (i * 256 + tid) * 8;
                int row = flat / BN, col = flat % BN;
                uint4 val = *(const uint4*)&Cs[row * PITCH + col];
                size_t oi = (size_t)blockIdx.z * sC + (size_t)(bm + g * 32 + row) * N + bn + col;
                *(uint4*)&Cg[oi] = val;
            }
        }
    } else {
#pragma unroll
        for (int n = 0; n < FN; n++) {
            const int ccol = bn + wc * FN * 16 + n * 16 + lrow;
            float bv = HBIAS ? bias[ccol] : 0.f;
#pragma unroll
            for (int m = 0; m < FM; m++) {
#pragma unroll
                for (int j = 0; j < 4; j++) {
                    const int rrow = bm + wr * FM * 16 + m * 16 + r0 + j;
                    float v = acc[m][n][j] + bv;
                    if (HSP)   v = softplusf_(v);
                    if (HGELU) v = geluf_(v);
                    if (HRES)  v += res[(size_t)rrow * N + ccol];
                    ((float*)C)[(size_t)blockIdx.z * sC + (size_t)rrow * N + ccol] = v;
                }
            }
        }
    }
}

// ---------- split-K partial reduce: proj = bf16(sum_z xpp[z]) ----------
__global__ __launch_bounds__(256) void xred_k(const float* __restrict__ p,
                                              unsigned short* __restrict__ o) {
    int i = blockIdx.x * 256 + threadIdx.x;   // over 8192*64/4 float4 groups
    const float4* p4 = (const float4*)p;
    float4 s = p4[i];
#pragma unroll
    for (int z = 1; z < 8; z++) {
        float4 t = p4[z * 131072 + i];
        s.x += t.x; s.y += t.y; s.z += t.z; s.w += t.w;
    }
    unsigned short ob[4] = {f2b(s.x), f2b(s.y), f2b(s.z), f2b(s.w)};
    *(unsigned long long*)&o[(size_t)i * 4] = *(unsigned long long*)ob;
}

// ---------- depthwise causal conv1d (width 4) + bias + silu (r11-best) ----------
__global__ __launch_bounds__(256) void conv_k(const unsigned short* __restrict__ uz,
                                              const float* __restrict__ w,
                                              const float* __restrict__ cb,
                                              unsigned short* __restrict__ u) {
    int t = blockIdx.x * 256 + threadIdx.x;     // over 2048 row-quads * 128 dgroups
    int dg = t & 127;
    int r4 = t >> 7;
    int l0 = (r4 & 63) * 4;
    size_t row0 = (size_t)r4 * 4;
    int d0 = dg * 8;

    float4 wv[8];
#pragma unroll
    for (int j = 0; j < 8; j++) wv[j] = ((const float4*)w)[d0 + j];
    float cbv[8];
#pragma unroll
    for (int j = 0; j < 8; j++) cbv[j] = cb[d0 + j];

    uint4 rows[7];
#pragma unroll
    for (int i = 0; i < 7; i++) {
        int ls = l0 + i - 3;
        if (ls >= 0) rows[i] = *(const uint4*)(uz + ((row0 + i - 3) << 11) + d0);
        else         rows[i] = make_uint4(0u, 0u, 0u, 0u);
    }

#pragma unroll
    for (int o = 0; o < 4; o++) {
        float acc[8];
#pragma unroll
        for (int j = 0; j < 8; j++) acc[j] = cbv[j];
#pragma unroll
        for (int k = 0; k < 4; k++) {
            const unsigned short* vs = (const unsigned short*)&rows[o + k];
#pragma unroll
            for (int j = 0; j < 8; j++)
                acc[j] = fmaf(((const float*)&wv[j])[k], b2f(vs[j]), acc[j]);
        }
        unsigned short ob[8];
#pragma unroll
        for (int j = 0; j < 8; j++) {
            float a = acc[j];
            ob[j] = f2b(a * sigmoidf_(a));
        }
        *(uint4*)(u + ((row0 + o) << 10) + d0) = *(const uint4*)ob;
    }
}

// ---------- chunked selective scan (NC=8 chunks of LC=32), dt bf16 (r6-verified) ----------
__global__ __launch_bounds__(256) void scan1_k(
    const unsigned short* __restrict__ dt,
    const unsigned short* __restrict__ u,
    const unsigned short* __restrict__ proj,   // B at 32..47
    const float* __restrict__ A_log,
    float* __restrict__ hend, float* __restrict__ Sc) {
    const int dg = blockIdx.x, c = blockIdx.y, b = blockIdx.z;
    const int d = dg * 256 + threadIdx.x;
    const size_t base = (size_t)b * 256 + c * 32;
    __shared__ float Bs[32][16];
    for (int i = threadIdx.x; i < 512; i += 256) {
        int r = i >> 4, s = i & 15;
        Bs[r][s] = b2f(proj[(base + r) * 64 + 32 + s]);
    }
    __syncthreads();
    float Aa[16];
#pragma unroll
    for (int s = 0; s < 16; s++) Aa[s] = -__expf(A_log[d * 16 + s]);
    float h[16];
#pragma unroll
    for (int s = 0; s < 16; s++) h[s] = 0.f;
    float ssum = 0.f;
    for (int l = 0; l < 32; l++) {
        size_t row = base + l;
        float dtv = b2f(dt[(row << 10) + d]);
        float uu  = b2f(u[(row << 10) + d]);
        float du  = dtv * uu;
        ssum += dtv;
#pragma unroll
        for (int s = 0; s < 16; s++)
            h[s] = __expf(dtv * Aa[s]) * h[s] + du * Bs[l][s];
    }
    size_t o = (size_t)(b * 8 + c) * 1024 + d;
    Sc[o] = ssum;
#pragma unroll
    for (int s = 0; s < 16; s++) hend[o * 16 + s] = h[s];
}

__global__ __launch_bounds__(256) void scan2_k(
    const float* __restrict__ hend, const float* __restrict__ Sc,
    const float* __restrict__ A_log, float* __restrict__ hstart) {
    const int d = blockIdx.x * 256 + threadIdx.x;
    const int b = blockIdx.y;
    float Aa[16];
#pragma unroll
    for (int s = 0; s < 16; s++) Aa[s] = -__expf(A_log[d * 16 + s]);
    float h[16];
#pragma unroll
    for (int s = 0; s < 16; s++) h[s] = 0.f;
    for (int c = 0; c < 8; c++) {
        size_t o = (size_t)(b * 8 + c) * 1024 + d;
#pragma unroll
        for (int s = 0; s < 16; s++) hstart[o * 16 + s] = h[s];
        float sc = Sc[o];
#pragma unroll
        for (int s = 0; s < 16; s++)
            h[s] = __expf(sc * Aa[s]) * h[s] + hend[o * 16 + s];
    }
}

__global__ __launch_bounds__(256) void scan3_k(
    const unsigned short* __restrict__ dt,
    const unsigned short* __restrict__ u,
    const unsigned short* __restrict__ uz,     // z at col 1024+d
    const unsigned short* __restrict__ proj,   // B at 32..47, C at 48..63
    const float* __restrict__ A_log,
    const float* __restrict__ Dp,
    const float* __restrict__ hstart,
    unsigned short* __restrict__ yg) {
    const int dg = blockIdx.x, c = blockIdx.y, b = blockIdx.z;
    const int d = dg * 256 + threadIdx.x;
    const size_t base = (size_t)b * 256 + c * 32;
    __shared__ float BCs[32][32];
    for (int i = threadIdx.x; i < 1024; i += 256) {
        int r = i >> 5, s = i & 31;
        BCs[r][s] = b2f(proj[(base + r) * 64 + 32 + s]);
    }
    __syncthreads();
    float Aa[16];
#pragma unroll
    for (int s = 0; s < 16; s++) Aa[s] = -__expf(A_log[d * 16 + s]);
    const float Dd = Dp[d];
    float h[16];
    size_t ho = ((size_t)(b * 8 + c) * 1024 + d) * 16;
#pragma unroll
    for (int s = 0; s < 16; s++) h[s] = hstart[ho + s];
    for (int l = 0; l < 32; l++) {
        size_t row = base + l;
        float dtv = b2f(dt[(row << 10) + d]);
        float uu  = b2f(u[(row << 10) + d]);
        float zz  = b2f(uz[(row << 11) + 1024 + d]);
        float du  = dtv * uu;
        float y = 0.f;
#pragma unroll
        for (int s = 0; s < 16; s++) {
            h[s] = __expf(dtv * Aa[s]) * h[s] + du * BCs[l][s];
            y = fmaf(h[s], BCs[l][16 + s], y);
        }
        y = fmaf(uu, Dd, y);
        yg[(row << 10) + d] = f2b(y * (zz * sigmoidf_(zz)));
    }
}

// ---------- layernorm ----------
template<int HRES, int OF32, int OBF>
__global__ __launch_bounds__(256) void ln_k(const float* __restrict__ xin,
                                            const float* __restrict__ resin,
                                            const float* __restrict__ g,
                                            const float* __restrict__ b,
                                            float* __restrict__ outf,
                                            unsigned short* __restrict__ outb) {
    const int row = blockIdx.x, tid = threadIdx.x;
    float2 v = ((const float2*)(xin + (size_t)row * 512))[tid];
    if (HRES) {
        float2 r2 = ((const float2*)(resin + (size_t)row * 512))[tid];
        v.x += r2.x; v.y += r2.y;
    }
    float s = v.x + v.y, q = v.x * v.x + v.y * v.y;
#pragma unroll
    for (int o = 32; o > 0; o >>= 1) { s += __shfl_xor(s, o); q += __shfl_xor(q, o); }
    __shared__ float sm[4], qm[4];
    const int lane = tid & 63, wv = tid >> 6;
    if (lane == 0) { sm[wv] = s; qm[wv] = q; }
    __syncthreads();
    s = sm[0] + sm[1] + sm[2] + sm[3];
    q = qm[0] + qm[1] + qm[2] + qm[3];
    const float mu = s * (1.f / 512.f);
    const float ri = rsqrtf(q * (1.f / 512.f) - mu * mu + 1e-5f);
    float2 gg = ((const float2*)g)[tid];
    float2 bb = ((const float2*)b)[tid];
    float o0 = (v.x - mu) * ri * gg.x + bb.x;
    float o1 = (v.y - mu) * ri * gg.y + bb.y;
    if (OF32) ((float2*)(outf + (size_t)row * 512))[tid] = make_float2(o0, o1);
    if (OBF) {
        unsigned short* ob = outb + (size_t)row * 512 + tid * 2;
        ob[0] = f2b(o0); ob[1] = f2b(o1);
    }
}

// ---------- fused double layernorm: x2 = LN_s(mout); h = LN_f(x2) ----------
__global__ __launch_bounds__(256) void lnln_k(const float* __restrict__ xin,
                                              const float* __restrict__ g1,
                                              const float* __restrict__ b1,
                                              const float* __restrict__ g2,
                                              const float* __restrict__ b2,
                                              float* __restrict__ x2out,
                                              unsigned short* __restrict__ hout) {
    const int row = blockIdx.x, tid = threadIdx.x;
    const int lane = tid & 63, wv = tid >> 6;
    __shared__ float sm[4], qm[4];

    float2 v = ((const float2*)(xin + (size_t)row * 512))[tid];
    float s = v.x + v.y, q = v.x * v.x + v.y * v.y;
#pragma unroll
    for (int o = 32; o > 0; o >>= 1) { s += __shfl_xor(s, o); q += __shfl_xor(q, o); }
    if (lane == 0) { sm[wv] = s; qm[wv] = q; }
    __syncthreads();
    s = sm[0] + sm[1] + sm[2] + sm[3];
    q = qm[0] + qm[1] + qm[2] + qm[3];
    float mu = s * (1.f / 512.f);
    float ri = rsqrtf(q * (1.f / 512.f) - mu * mu + 1e-5f);
    float2 gg = ((const float2*)g1)[tid];
    float2 bb = ((const float2*)b1)[tid];
    float o0 = (v.x - mu) * ri * gg.x + bb.x;
    float o1 = (v.y - mu) * ri * gg.y + bb.y;
    ((float2*)(x2out + (size_t)row * 512))[tid] = make_float2(o0, o1);

    // second LN over (o0,o1)
    __syncthreads();
    s = o0 + o1; q = o0 * o0 + o1 * o1;
#pragma unroll
    for (int o = 32; o > 0; o >>= 1) { s += __shfl_xor(s, o); q += __shfl_xor(q, o); }
    if (lane == 0) { sm[wv] = s; qm[wv] = q; }
    __syncthreads();
    s = sm[0] + sm[1] + sm[2] + sm[3];
    q = qm[0] + qm[1] + qm[2] + qm[3];
    mu = s * (1.f / 512.f);
    ri = rsqrtf(q * (1.f / 512.f) - mu * mu + 1e-5f);
    gg = ((const float2*)g2)[tid];
    bb = ((const float2*)b2)[tid];
    float h0 = (o0 - mu) * ri * gg.x + bb.x;
    float h1 = (o1 - mu) * ri * gg.y + bb.y;
    unsigned short* ob = hout + (size_t)row * 512 + tid * 2;
    ob[0] = f2b(h0); ob[1] = f2b(h1);
}

// ---------- per-batch transpose x1 (b,l,d) f32 -> (b,d,l) bf16 ----------
__global__ __launch_bounds__(256) void trans_k(const float* __restrict__ x1,
                                               unsigned short* __restrict__ xt) {
    __shared__ float tile[32][33];
    const int b = blockIdx.z;
    const int d0 = blockIdx.x * 32, l0 = blockIdx.y * 32;
    const int c = threadIdx.x & 31, r = threadIdx.x >> 5;
    const float* src = x1 + ((size_t)b * 256 + l0) * 512 + d0;
#pragma unroll
    for (int i = 0; i < 4; i++) tile[r + i * 8][c] = src[(size_t)(r + i * 8) * 512 + c];
    __syncthreads();
    unsigned short* dst = xt + ((size_t)b * 512 + d0) * 256 + l0;
#pragma unroll
    for (int i = 0; i < 4; i++) dst[(size_t)(r + i * 8) * 256 + c] = f2b(tile[c][r + i * 8]);
}

// ---------- workspace layout (bytes) ----------
constexpr size_t OFF_WT_DIN  = 0;
constexpr size_t OFF_WT_SIN  = OFF_WT_DIN  + 2048ull * 512 * 2;
constexpr size_t OFF_WT_DOUT = OFF_WT_SIN  + 2048ull * 512 * 2;
constexpr size_t OFF_WT_SOUT = OFF_WT_DOUT + 512ull * 1024 * 2;
constexpr size_t OFF_WT_F1   = OFF_WT_SOUT + 512ull * 1024 * 2;
constexpr size_t OFF_WT_F2   = OFF_WT_F1   + 2048ull * 512 * 2;
constexpr size_t OFF_XPT_D   = OFF_WT_F2   + 512ull * 2048 * 2;   // xproj^T (64,1024) bf16
constexpr size_t OFF_XPT_S   = OFF_XPT_D   + 64ull * 1024 * 2;
constexpr size_t OFF_DTT_D   = OFF_XPT_S   + 64ull * 1024 * 2;    // dtw^T (1024,32) bf16
constexpr size_t OFF_DTT_S   = OFF_DTT_D   + 1024ull * 32 * 2;
constexpr size_t OFF_ACT     = OFF_DTT_S   + 1024ull * 32 * 2;    // xd / xg bf16 (8192x512)
constexpr size_t OFF_UZ      = OFF_ACT  + 8192ull * 512 * 2;      // uz bf16 (8192x2048); reused FFN mid
constexpr size_t OFF_U       = OFF_UZ   + 8192ull * 2048 * 2;     // u bf16 (8192x1024); reused h bf16
constexpr size_t OFF_PROJ    = OFF_U    + 8192ull * 1024 * 2;     // proj bf16 (8192x64)
constexpr size_t OFF_YG      = OFF_PROJ + 8192ull * 64 * 2;       // gated y bf16 (8192x1024)
constexpr size_t OFF_MOUT    = OFF_YG   + 8192ull * 1024 * 2;     // mamba out f32; reused as hend
constexpr size_t OFF_X1      = OFF_MOUT + 8192ull * 512 * 4;      // x1 f32
constexpr size_t OFF_X2      = OFF_X1   + 8192ull * 512 * 4;      // x2 f32
constexpr size_t OFF_X1T     = OFF_X2   + 8192ull * 512 * 4;      // x1^T bf16 (32,512,256)
constexpr size_t OFF_ADJB    = OFF_X1T  + 32ull * 512 * 256 * 2;  // adj bf16 (256x256)
constexpr size_t OFF_DT      = OFF_ADJB + 256ull * 256 * 2;       // dt bf16 (16MB) / xpp f32 partials (16MB)
constexpr size_t OFF_HST     = OFF_DT   + 8192ull * 1024 * 2;     // hstart (32,8,1024,16) f32
constexpr size_t OFF_SC      = OFF_HST  + 32ull * 8 * 1024 * 16 * 4; // Sc (32,8,1024) f32

extern "C" void kernel_launch(void* const* d_in, const int* in_sizes, int n_in,
                              void* d_out, int out_size, void* d_ws, size_t ws_size,
                              hipStream_t stream) {
    (void)in_sizes; (void)n_in; (void)out_size; (void)ws_size;
    const float* x      = (const float*)d_in[0];
    const float* dinw   = (const float*)d_in[1];
    const float* dconvw = (const float*)d_in[2];
    const float* dconvb = (const float*)d_in[3];
    const float* dxproj = (const float*)d_in[4];
    const float* ddtw   = (const float*)d_in[5];
    const float* ddtb   = (const float*)d_in[6];
    const float* dAlog  = (const float*)d_in[7];
    const float* dD     = (const float*)d_in[8];
    const float* doutw  = (const float*)d_in[9];
    const float* dlng   = (const float*)d_in[10];
    const float* dlnb   = (const float*)d_in[11];
    const float* sinw   = (const float*)d_in[12];
    const float* sconvw = (const float*)d_in[13];
    const float* sconvb = (const float*)d_in[14];
    const float* sxproj = (const float*)d_in[15];
    const float* sdtw   = (const float*)d_in[16];
    const float* sdtb   = (const float*)d_in[17];
    const float* sAlog  = (const float*)d_in[18];
    const float* sD     = (const float*)d_in[19];
    const float* soutw  = (const float*)d_in[20];
    const float* slng   = (const float*)d_in[21];
    const float* slnb   = (const float*)d_in[22];
    const float* semb1  = (const float*)d_in[23];
    const float* semb2  = (const float*)d_in[24];
    const float* flng   = (const float*)d_in[25];
    const float* flnb   = (const float*)d_in[26];
    const float* fw1    = (const float*)d_in[27];
    const float* fb1    = (const float*)d_in[28];
    const float* fw2    = (const float*)d_in[29];
    const float* fb2    = (const float*)d_in[30];

    char* ws = (char*)d_ws;
    unsigned short* wtDin  = (unsigned short*)(ws + OFF_WT_DIN);
    unsigned short* wtSin  = (unsigned short*)(ws + OFF_WT_SIN);
    unsigned short* wtDout = (unsigned short*)(ws + OFF_WT_DOUT);
    unsigned short* wtSout = (unsigned short*)(ws + OFF_WT_SOUT);
    unsigned short* wtF1   = (unsigned short*)(ws + OFF_WT_F1);
    unsigned short* wtF2   = (unsigned short*)(ws + OFF_WT_F2);
    unsigned short* xptD   = (unsigned short*)(ws + OFF_XPT_D);
    unsigned short* xptS   = (unsigned short*)(ws + OFF_XPT_S);
    unsigned short* dttD   = (unsigned short*)(ws + OFF_DTT_D);
    unsigned short* dttS   = (unsigned short*)(ws + OFF_DTT_S);
    unsigned short* actIn  = (unsigned short*)(ws + OFF_ACT);
    unsigned short* uzBuf  = (unsigned short*)(ws + OFF_UZ);
    unsigned short* uBuf   = (unsigned short*)(ws + OFF_U);
    unsigned short* projB  = (unsigned short*)(ws + OFF_PROJ);
    unsigned short* ygBuf  = (unsigned short*)(ws + OFF_YG);
    float*          moutB  = (float*)(ws + OFF_MOUT);
    float*          hendB  = moutB;                        // reuse (dead until out-GEMM)
    float*          x1Buf  = (float*)(ws + OFF_X1);
    float*          x2Buf  = (float*)(ws + OFF_X2);
    unsigned short* x1tBuf = (unsigned short*)(ws + OFF_X1T);
    unsigned short* adjB   = (unsigned short*)(ws + OFF_ADJB);
    unsigned short* dtBuf  = (unsigned short*)(ws + OFF_DT);
    float*          xppBuf = (float*)(ws + OFF_DT);   // xproj split-K partials; dead before dt-GEMM writes
    float*          hstB   = (float*)(ws + OFF_HST);
    float*          scB    = (float*)(ws + OFF_SC);
    unsigned short* hBuf   = uBuf;    // reuse (u dead after scan)
    unsigned short* midBuf = uzBuf;   // reuse (uz dead after scan)

    float* outX   = (float*)d_out;
    float* outAdj = outX + 4194304;

    // 1) weight transposes/converts
    WtArgs wa;
    wa.m[0]  = WtDesc{dinw,   wtDin,  512,  2048, 0};
    wa.m[1]  = WtDesc{sinw,   wtSin,  512,  2048, 1024};
    wa.m[2]  = WtDesc{doutw,  wtDout, 1024, 512,  2048};
    wa.m[3]  = WtDesc{soutw,  wtSout, 1024, 512,  2560};
    wa.m[4]  = WtDesc{fw1,    wtF1,   512,  2048, 3072};
    wa.m[5]  = WtDesc{fw2,    wtF2,   2048, 512,  4096};
    wa.m[6]  = WtDesc{dxproj, xptD,   1024, 64,   5120};
    wa.m[7]  = WtDesc{sxproj, xptS,   1024, 64,   5184};
    wa.m[8]  = WtDesc{ddtw,   dttD,   32,   1024, 5248};
    wa.m[9]  = WtDesc{sdtw,   dttS,   32,   1024, 5280};
    wa.m[10] = WtDesc{dinw,   wtDin,  512,  2048, 0x7fffffff};
    wa.m[11] = WtDesc{dinw,   wtDin,  512,  2048, 0x7fffffff};
    wtrans_k<<<dim3(5312), dim3(256), 0, stream>>>(wa);

    diff_k<<<dim3(4096), dim3(256), 0, stream>>>(x, actIn);
    adj_k<<<dim3(256), dim3(256), 0, stream>>>(semb1, semb2, outAdj, adjB);

    // ---- stage 1: DiffSSM mamba ----
    gemm256_k<0,0><<<dim3(32,8), dim3(512), 0, stream>>>(
        actIn, wtDin, uzBuf, nullptr, 8192, 2048, 512, 512);
    conv_k<<<dim3(1024), dim3(256), 0, stream>>>(uzBuf, dconvw, dconvb, uBuf);
    // xproj: split-K x8 (each part K=128, 2 iters), f32 partials -> reduce to bf16
    gemm_k<64,64,64,2,2,2, 0,0,0,0,0><<<dim3(128,1,8), dim3(256), 0, stream>>>(
        uBuf, xptD, xppBuf, nullptr, nullptr, 8192, 64, 128, 1024, 1024, 128, 128, 524288);
    xred_k<<<dim3(512), dim3(256), 0, stream>>>(xppBuf, projB);
    // dt = softplus(proj[:,0:32] @ dtw^T + dtb), bf16 out (r6-verified numerics)
    gemm_k<128,128,32,2,4,4, 1,1,0,0,1><<<dim3(64,8,1), dim3(256), 0, stream>>>(
        projB, dttD, dtBuf, ddtb, nullptr, 8192, 1024, 32, 64, 32, 0, 0, 0);
    scan1_k<<<dim3(4,8,32), dim3(256), 0, stream>>>(dtBuf, uBuf, projB, dAlog, hendB, scB);
    scan2_k<<<dim3(4,32),   dim3(256), 0, stream>>>(hendB, scB, dAlog, hstB);
    scan3_k<<<dim3(4,8,32), dim3(256), 0, stream>>>(dtBuf, uBuf, uzBuf, projB, dAlog, dD, hstB, ygBuf);
    // out-GEMM with fused residual (+x), f32 out
    gemm_k<128,128,64,2,4,4, 0,0,0,1,0><<<dim3(64,4,1), dim3(256), 0, stream>>>(
        ygBuf, wtDout, moutB, nullptr, x, 8192, 512, 1024, 1024, 1024, 0, 0, 0);
    ln_k<0,1,0><<<dim3(8192), dim3(256), 0, stream>>>(moutB, nullptr, dlng, dlnb, x1Buf, nullptr);

    // ---- stage 2: SpatialGraphMamba ----
    trans_k<<<dim3(16,8,32), dim3(256), 0, stream>>>(x1Buf, x1tBuf);
    gemm_k<128,128,64,2,4,4, 1,0,0,0,0><<<dim3(2,4,32), dim3(256), 0, stream>>>(
        adjB, x1tBuf, actIn, nullptr, nullptr, 256, 512, 256, 256, 256, 0, 131072, 131072);
    gemm256_k<0,0><<<dim3(32,8), dim3(512), 0, stream>>>(
        actIn, wtSin, uzBuf, nullptr, 8192, 2048, 512, 512);
    conv_k<<<dim3(1024), dim3(256), 0, stream>>>(uzBuf, sconvw, sconvb, uBuf);
    gemm_k<64,64,64,2,2,2, 0,0,0,0,0><<<dim3(128,1,8), dim3(256), 0, stream>>>(
        uBuf, xptS, xppBuf, nullptr, nullptr, 8192, 64, 128, 1024, 1024, 128, 128, 524288);
    xred_k<<<dim3(512), dim3(256), 0, stream>>>(xppBuf, projB);
    gemm_k<128,128,32,2,4,4, 1,1,0,0,1><<<dim3(64,8,1), dim3(256), 0, stream>>>(
        projB, dttS, dtBuf, sdtb, nullptr, 8192, 1024, 32, 64, 32, 0, 0, 0);
    scan1_k<<<dim3(4,8,32), dim3(256), 0, stream>>>(dtBuf, uBuf, projB, sAlog, hendB, scB);
    scan2_k<<<dim3(4,32),   dim3(256), 0, stream>>>(hendB, scB, sAlog, hstB);
    scan3_k<<<dim3(4,8,32), dim3(256), 0, stream>>>(dtBuf, uBuf, uzBuf, projB, sAlog, sD, hstB, ygBuf);
    gemm_k<128,128,64,2,4,4, 0,0,0,1,0><<<dim3(64,4,1), dim3(256), 0, stream>>>(
        ygBuf, wtSout, moutB, nullptr, x1Buf, 8192, 512, 1024, 1024, 1024, 0, 0, 0);
    // fused: x2 = LN_s(mout); h = LN_f(x2)
    lnln_k<<<dim3(8192), dim3(256), 0, stream>>>(moutB, slng, slnb, flng, flnb, x2Buf, hBuf);

    // ---- stage 3: FFN ----
    gemm256_k<1,1><<<dim3(32,8), dim3(512), 0, stream>>>(
        hBuf, wtF1, midBuf, fb1, 8192, 2048, 512, 512);
    gemm_k<128,128,64,2,4,4, 0,1,0,1,0><<<dim3(64,4,1), dim3(256), 0, stream>>>(
        midBuf, wtF2, outX, fb2, x2Buf, 8192, 512, 2048, 2048, 2048, 0, 0, 0);
}

// Round 14
// 534.088 us; speedup vs baseline: 1.1245x; 1.1245x over previous
//
#include <hip/hip_runtime.h>

#define DEV __device__ __forceinline__

typedef __bf16 bf16x8 __attribute__((ext_vector_type(8)));
typedef float  f32x4  __attribute__((ext_vector_type(4)));

// ---------- helpers ----------
DEV unsigned short f2b(float f) {                 // f32 -> bf16 (RNE)
    union { float f; unsigned u; } v; v.f = f;
    unsigned r = v.u + 0x7fffu + ((v.u >> 16) & 1u);
    return (unsigned short)(r >> 16);
}
DEV float b2f(unsigned short h) {
    union { unsigned u; float f; } v; v.u = ((unsigned)h) << 16;
    return v.f;
}
DEV float sigmoidf_(float x) { return 1.f / (1.f + __expf(-x)); }
DEV float geluf_(float x) {                       // jax default: tanh approximation
    float t = 0.7978845608028654f * (x + 0.044715f * x * x * x);
    return 0.5f * x * (1.f + tanhf(t));
}
DEV float softplusf_(float x) { return x > 15.f ? x : log1pf(__expf(x)); }
DEV void gload_lds16(const void* g, void* l) {
    __builtin_amdgcn_global_load_lds((const __attribute__((address_space(1))) void*)g,
                                     (__attribute__((address_space(3))) void*)l, 16, 0, 0);
}

// ---------- problem constants ----------
// B=32 L=256 D=512 D_INNER=1024 D_STATE=16 DT_RANK=32 D_FF=2048, M = B*L = 8192
// proj layout (64 cols): [dt(32) | B(16) | C(16)]

// ---------- weight transpose+convert: W (K,N) f32 -> W^T (N,K) bf16 ----------
struct WtDesc { const float* s; unsigned short* d; int K; int N; int t0; };
struct WtArgs { WtDesc m[12]; };

__global__ __launch_bounds__(256) void wtrans_k(WtArgs a) {
    __shared__ float tile[32][33];
    int t = blockIdx.x;
    int mi = 0;
#pragma unroll
    for (int j = 1; j < 12; j++) if (t >= a.m[j].t0) mi = j;
    const float* src0 = a.m[mi].s;
    unsigned short* dst0 = a.m[mi].d;
    const int K = a.m[mi].K, N = a.m[mi].N;
    const int lt = t - a.m[mi].t0;
    const int ntk = K >> 5;
    const int kt = lt % ntk, nt = lt / ntk;
    const int c = threadIdx.x & 31, r = threadIdx.x >> 5;
    const float* src = src0 + (size_t)(kt * 32) * N + nt * 32;
#pragma unroll
    for (int i = 0; i < 4; i++) tile[r + i * 8][c] = src[(size_t)(r + i * 8) * N + c];
    __syncthreads();
    unsigned short* dst = dst0 + (size_t)(nt * 32) * K + kt * 32;
#pragma unroll
    for (int i = 0; i < 4; i++) dst[(size_t)(r + i * 8) * K + c] = f2b(tile[c][r + i * 8]);
}

// ---------- xd = causal diff of x, emitted bf16 (4 elems/thread) ----------
__global__ __launch_bounds__(256) void diff_k(const float* __restrict__ x,
                                              unsigned short* __restrict__ xd) {
    size_t i4 = (size_t)blockIdx.x * 256 + threadIdx.x;
    size_t idx = i4 * 4;
    int l = (int)((idx >> 9) & 255);
    float4 v = *(const float4*)&x[idx];
    if (l > 0) {
        float4 p = *(const float4*)&x[idx - 512];
        v.x -= p.x; v.y -= p.y; v.z -= p.z; v.w -= p.w;
    }
    unsigned short o[4] = {f2b(v.x), f2b(v.y), f2b(v.z), f2b(v.w)};
    *(unsigned long long*)&xd[idx] = *(unsigned long long*)o;
}

// ---------- adjacency: softmax(relu(e1 @ e2^T)) ----------
__global__ __launch_bounds__(256) void adj_k(const float* __restrict__ e1,
                                             const float* __restrict__ e2,
                                             float* __restrict__ adjf,
                                             unsigned short* __restrict__ adjb) {
    const int n = blockIdx.x, tid = threadIdx.x;
    __shared__ float e1s[16];
    __shared__ float redm[4], reds[4];
    if (tid < 16) e1s[tid] = e1[n * 16 + tid];
    __syncthreads();
    const float* e2r = e2 + tid * 16;
    float dot = 0.f;
#pragma unroll
    for (int k = 0; k < 16; k++) dot = fmaf(e1s[k], e2r[k], dot);
    float v = fmaxf(dot, 0.f);
    float m = v;
#pragma unroll
    for (int o = 32; o > 0; o >>= 1) m = fmaxf(m, __shfl_xor(m, o));
    const int lane = tid & 63, wv = tid >> 6;
    if (lane == 0) redm[wv] = m;
    __syncthreads();
    m = fmaxf(fmaxf(redm[0], redm[1]), fmaxf(redm[2], redm[3]));
    float e = __expf(v - m);
    float ssum = e;
#pragma unroll
    for (int o = 32; o > 0; o >>= 1) ssum += __shfl_xor(ssum, o);
    if (lane == 0) reds[wv] = ssum;
    __syncthreads();
    ssum = reds[0] + reds[1] + reds[2] + reds[3];
    float o = e / ssum;
    adjf[(size_t)n * 256 + tid] = o;
    adjb[(size_t)n * 256 + tid] = f2b(o);
}

// ---------- 256x256 bf16 MFMA GEMM, 8 waves, dbuf 2-phase prefetch (r5-best) ----------
template<int HBIAS, int HGELU>
__global__ __launch_bounds__(512, 2) void gemm256_k(
    const unsigned short* __restrict__ A, const unsigned short* __restrict__ Bt,
    unsigned short* __restrict__ C, const float* __restrict__ bias,
    int M, int N, int K, int lda) {
    constexpr int BM = 256, BN = 256, BK = 64;
    __shared__ __align__(16) unsigned short As[2][BM * BK];
    __shared__ __align__(16) unsigned short Bs[2][BN * BK];
    const int tid  = threadIdx.x;
    const int lane = tid & 63;
    const int wave = tid >> 6;
    const int wr = wave >> 2;
    const int wc = wave & 3;
    const int bm = blockIdx.x * BM, bn = blockIdx.y * BN;
    const int lrow  = lane & 15;
    const int klane = lane >> 4;

    f32x4 acc[8][4];
#pragma unroll
    for (int m = 0; m < 8; m++)
#pragma unroll
        for (int n = 0; n < 4; n++) {
            acc[m][n][0] = 0.f; acc[m][n][1] = 0.f; acc[m][n][2] = 0.f; acc[m][n][3] = 0.f;
        }

    auto STAGE = [&](int buf, int k0) {
#pragma unroll
        for (int it = 0; it < 4; ++it) {
            int flat = (it * 512 + tid) * 8;
            int r = flat >> 6, s = (flat & 63) >> 3;
            int c = (s ^ (r & 7)) * 8;
            gload_lds16(A + (size_t)(bm + r) * lda + (k0 + c),
                        &As[buf][(it * 512 + (tid & 448)) * 8]);
        }
#pragma unroll
        for (int it = 0; it < 4; ++it) {
            int flat = (it * 512 + tid) * 8;
            int r = flat >> 6, s = (flat & 63) >> 3;
            int c = (s ^ (r & 7)) * 8;
            gload_lds16(Bt + (size_t)(bn + r) * K + (k0 + c),
                        &Bs[buf][(it * 512 + (tid & 448)) * 8]);
        }
    };
    auto COMPUTE = [&](int buf) {
#pragma unroll
        for (int kk = 0; kk < 2; kk++) {
            bf16x8 af[8], bfv[4];
#pragma unroll
            for (int m = 0; m < 8; m++) {
                int rr = wr * 128 + m * 16 + lrow;
                int sl = (kk * 4 + klane) ^ (rr & 7);
                af[m] = *(const bf16x8*)&As[buf][rr * BK + sl * 8];
            }
#pragma unroll
            for (int n = 0; n < 4; n++) {
                int rr = wc * 64 + n * 16 + lrow;
                int sl = (kk * 4 + klane) ^ (rr & 7);
                bfv[n] = *(const bf16x8*)&Bs[buf][rr * BK + sl * 8];
            }
#pragma unroll
            for (int m = 0; m < 8; m++)
#pragma unroll
                for (int n = 0; n < 4; n++)
                    acc[m][n] = __builtin_amdgcn_mfma_f32_16x16x32_bf16(af[m], bfv[n], acc[m][n], 0, 0, 0);
        }
    };

    const int nt = K / BK;
    STAGE(0, 0);
    __syncthreads();
    for (int t = 0; t < nt; t += 2) {
        if (t + 1 < nt) STAGE(1, (t + 1) * BK);
        COMPUTE(0);
        __syncthreads();
        if (t + 1 < nt) {
            if (t + 2 < nt) STAGE(0, (t + 2) * BK);
            COMPUTE(1);
            if (t + 2 < nt) __syncthreads();
        }
    }

    // staged coalesced bf16 epilogue (reuses As[0]): 8 groups of 32 rows x 256 cols
    const int r0 = (lane >> 4) << 2;
    unsigned short* Cs = As[0];
    constexpr int PITCH = BN + 8;
#pragma unroll
    for (int g = 0; g < 8; g++) {
        __syncthreads();
        if (wr == (g >> 2)) {
#pragma unroll
            for (int mm = 0; mm < 2; mm++) {
                const int m = (g & 3) * 2 + mm;
#pragma unroll
                for (int n = 0; n < 4; n++) {
                    const int cl = wc * 64 + n * 16 + lrow;
                    float bv = HBIAS ? bias[bn + cl] : 0.f;
#pragma unroll
                    for (int j = 0; j < 4; j++) {
                        float v = acc[m][n][j] + bv;
                        if (HGELU) v = geluf_(v);
                        Cs[(mm * 16 + r0 + j) * PITCH + cl] = f2b(v);
                    }
                }
            }
        }
        __syncthreads();
#pragma unroll
        for (int i = 0; i < 2; i++) {
            int flat = (i * 512 + tid) * 8;
            int row = flat >> 8, col = flat & 255;
            uint4 val = *(const uint4*)&Cs[row * PITCH + col];
            *(uint4*)&C[(size_t)(bm + g * 32 + row) * N + bn + col] = val;
        }
    }
}

// ---------- 128-class bf16 MFMA GEMM (single-buffer 2-barrier; ldb decoupled) ----------
template<int BM, int BN, int BK, int WRN, int FM, int FN,
         int OBF, int HBIAS, int HGELU, int HRES, int HSP>
__global__ __launch_bounds__(256) void gemm_k(
    const unsigned short* __restrict__ A, const unsigned short* __restrict__ Bt,
    void* __restrict__ C, const float* __restrict__ bias, const float* __restrict__ res,
    int M, int N, int K, int lda, int ldb, long sA, long sB, long sC) {
    constexpr int SMASK = BK / 8 - 1;
    constexpr int KH    = BK / 32;
    __shared__ __align__(16) unsigned short As[BM * BK];
    __shared__ __align__(16) unsigned short Bs[BN * BK];
    const int tid  = threadIdx.x;
    const int lane = tid & 63;
    const int wave = tid >> 6;
    const int wr = wave / WRN, wc = wave % WRN;
    const int bm = blockIdx.x * BM, bn = blockIdx.y * BN;
    const unsigned short* Ab = A  + (size_t)blockIdx.z * sA;
    const unsigned short* Bb = Bt + (size_t)blockIdx.z * sB;
    const int lrow  = lane & 15;
    const int klane = lane >> 4;

    f32x4 acc[FM][FN];
#pragma unroll
    for (int m = 0; m < FM; m++)
#pragma unroll
        for (int n = 0; n < FN; n++) {
            acc[m][n][0] = 0.f; acc[m][n][1] = 0.f; acc[m][n][2] = 0.f; acc[m][n][3] = 0.f;
        }

    constexpr int AI = (BM * BK) / 2048;
    constexpr int BI = (BN * BK) / 2048;

    for (int k0 = 0; k0 < K; k0 += BK) {
#pragma unroll
        for (int it = 0; it < AI; ++it) {
            int flat = (it * 256 + tid) * 8;
            int r = flat / BK, s = (flat % BK) >> 3;
            int c = (s ^ (r & SMASK)) * 8;
            gload_lds16(Ab + (size_t)(bm + r) * lda + (k0 + c),
                        &As[(it * 256 + (tid & 192)) * 8]);
        }
#pragma unroll
        for (int it = 0; it < BI; ++it) {
            int flat = (it * 256 + tid) * 8;
            int r = flat / BK, s = (flat % BK) >> 3;
            int c = (s ^ (r & SMASK)) * 8;
            gload_lds16(Bb + (size_t)(bn + r) * ldb + (k0 + c),
                        &Bs[(it * 256 + (tid & 192)) * 8]);
        }
        __syncthreads();
#pragma unroll
        for (int kk = 0; kk < KH; kk++) {
            bf16x8 af[FM], bfv[FN];
#pragma unroll
            for (int m = 0; m < FM; m++) {
                int rr = wr * FM * 16 + m * 16 + lrow;
                int sl = (kk * 4 + klane) ^ (rr & SMASK);
                af[m] = *(const bf16x8*)&As[rr * BK + sl * 8];
            }
#pragma unroll
            for (int n = 0; n < FN; n++) {
                int rr = wc * FN * 16 + n * 16 + lrow;
                int sl = (kk * 4 + klane) ^ (rr & SMASK);
                bfv[n] = *(const bf16x8*)&Bs[rr * BK + sl * 8];
            }
#pragma unroll
            for (int m = 0; m < FM; m++)
#pragma unroll
                for (int n = 0; n < FN; n++)
                    acc[m][n] = __builtin_amdgcn_mfma_f32_16x16x32_bf16(af[m], bfv[n], acc[m][n], 0, 0, 0);
        }
        __syncthreads();
    }

    const int r0 = (lane >> 4) << 2;
    if (OBF) {
        unsigned short* Cs = Bs;
        constexpr int PITCH = BN + 8;
        unsigned short* Cg = (unsigned short*)C;
#pragma unroll
        for (int g = 0; g < BM / 32; g++) {
            __syncthreads();
            if (wr == (g * 2) / FM) {
                const int mb = (g * 2) % FM;
#pragma unroll
                for (int mm = 0; mm < 2; mm++) {
#pragma unroll
                    for (int n = 0; n < FN; n++) {
                        const int cl = wc * FN * 16 + n * 16 + lrow;
                        float bv = HBIAS ? bias[bn + cl] : 0.f;
#pragma unroll
                        for (int j = 0; j < 4; j++) {
                            float v = acc[mb + mm][n][j] + bv;
                            if (HSP)   v = softplusf_(v);
                            if (HGELU) v = geluf_(v);
                            Cs[(mm * 16 + r0 + j) * PITCH + cl] = f2b(v);
                        }
                    }
                }
            }
            __syncthreads();
#pragma unroll
            for (int i = 0; i < (32 * BN) / 2048; i++) {
                int flat = (i * 256 + tid) * 8;
                int row = flat / BN, col = flat % BN;
                uint4 val = *(const uint4*)&Cs[row * PITCH + col];
                size_t oi = (size_t)blockIdx.z * sC + (size_t)(bm + g * 32 + row) * N + bn + col;
                *(uint4*)&Cg[oi] = val;
            }
        }
    } else {
#pragma unroll
        for (int n = 0; n < FN; n++) {
            const int ccol = bn + wc * FN * 16 + n * 16 + lrow;
            float bv = HBIAS ? bias[ccol] : 0.f;
#pragma unroll
            for (int m = 0; m < FM; m++) {
#pragma unroll
                for (int j = 0; j < 4; j++) {
                    const int rrow = bm + wr * FM * 16 + m * 16 + r0 + j;
                    float v = acc[m][n][j] + bv;
                    if (HSP)   v = softplusf_(v);
                    if (HGELU) v = geluf_(v);
                    if (HRES)  v += res[(size_t)rrow * N + ccol];
                    ((float*)C)[(size_t)blockIdx.z * sC + (size_t)rrow * N + ccol] = v;
                }
            }
        }
    }
}

// ---------- split-K partial reduce: proj = bf16(sum_z xpp[z]) ----------
__global__ __launch_bounds__(256) void xred_k(const float* __restrict__ p,
                                              unsigned short* __restrict__ o) {
    int i = blockIdx.x * 256 + threadIdx.x;   // over 8192*64/4 float4 groups
    const float4* p4 = (const float4*)p;
    float4 s = p4[i];
#pragma unroll
    for (int z = 1; z < 8; z++) {
        float4 t = p4[z * 131072 + i];
        s.x += t.x; s.y += t.y; s.z += t.z; s.w += t.w;
    }
    unsigned short ob[4] = {f2b(s.x), f2b(s.y), f2b(s.z), f2b(s.w)};
    *(unsigned long long*)&o[(size_t)i * 4] = *(unsigned long long*)ob;
}

// ---------- depthwise causal conv1d (width 4) + bias + silu (r11-best) ----------
__global__ __launch_bounds__(256) void conv_k(const unsigned short* __restrict__ uz,
                                              const float* __restrict__ w,
                                              const float* __restrict__ cb,
                                              unsigned short* __restrict__ u) {
    int t = blockIdx.x * 256 + threadIdx.x;     // over 2048 row-quads * 128 dgroups
    int dg = t & 127;
    int r4 = t >> 7;
    int l0 = (r4 & 63) * 4;
    size_t row0 = (size_t)r4 * 4;
    int d0 = dg * 8;

    float4 wv[8];
#pragma unroll
    for (int j = 0; j < 8; j++) wv[j] = ((const float4*)w)[d0 + j];
    float cbv[8];
#pragma unroll
    for (int j = 0; j < 8; j++) cbv[j] = cb[d0 + j];

    uint4 rows[7];
#pragma unroll
    for (int i = 0; i < 7; i++) {
        int ls = l0 + i - 3;
        if (ls >= 0) rows[i] = *(const uint4*)(uz + ((row0 + i - 3) << 11) + d0);
        else         rows[i] = make_uint4(0u, 0u, 0u, 0u);
    }

#pragma unroll
    for (int o = 0; o < 4; o++) {
        float acc[8];
#pragma unroll
        for (int j = 0; j < 8; j++) acc[j] = cbv[j];
#pragma unroll
        for (int k = 0; k < 4; k++) {
            const unsigned short* vs = (const unsigned short*)&rows[o + k];
#pragma unroll
            for (int j = 0; j < 8; j++)
                acc[j] = fmaf(((const float*)&wv[j])[k], b2f(vs[j]), acc[j]);
        }
        unsigned short ob[8];
#pragma unroll
        for (int j = 0; j < 8; j++) {
            float a = acc[j];
            ob[j] = f2b(a * sigmoidf_(a));
        }
        *(uint4*)(u + ((row0 + o) << 10) + d0) = *(const uint4*)ob;
    }
}

// ---------- chunked selective scan (NC=8 chunks of LC=32), dt f32 (r12-proven) ----------
__global__ __launch_bounds__(256) void scan1_k(
    const float* __restrict__ dt,
    const unsigned short* __restrict__ u,
    const unsigned short* __restrict__ proj,   // B at 32..47
    const float* __restrict__ A_log,
    float* __restrict__ hend, float* __restrict__ Sc) {
    const int dg = blockIdx.x, c = blockIdx.y, b = blockIdx.z;
    const int d = dg * 256 + threadIdx.x;
    const size_t base = (size_t)b * 256 + c * 32;
    __shared__ float Bs[32][16];
    for (int i = threadIdx.x; i < 512; i += 256) {
        int r = i >> 4, s = i & 15;
        Bs[r][s] = b2f(proj[(base + r) * 64 + 32 + s]);
    }
    __syncthreads();
    float Aa[16];
#pragma unroll
    for (int s = 0; s < 16; s++) Aa[s] = -__expf(A_log[d * 16 + s]);
    float h[16];
#pragma unroll
    for (int s = 0; s < 16; s++) h[s] = 0.f;
    float ssum = 0.f;
    for (int l = 0; l < 32; l++) {
        size_t row = base + l;
        float dtv = dt[(row << 10) + d];
        float uu  = b2f(u[(row << 10) + d]);
        float du  = dtv * uu;
        ssum += dtv;
#pragma unroll
        for (int s = 0; s < 16; s++)
            h[s] = __expf(dtv * Aa[s]) * h[s] + du * Bs[l][s];
    }
    size_t o = (size_t)(b * 8 + c) * 1024 + d;
    Sc[o] = ssum;
#pragma unroll
    for (int s = 0; s < 16; s++) hend[o * 16 + s] = h[s];
}

__global__ __launch_bounds__(256) void scan2_k(
    const float* __restrict__ hend, const float* __restrict__ Sc,
    const float* __restrict__ A_log, float* __restrict__ hstart) {
    const int d = blockIdx.x * 256 + threadIdx.x;
    const int b = blockIdx.y;
    float Aa[16];
#pragma unroll
    for (int s = 0; s < 16; s++) Aa[s] = -__expf(A_log[d * 16 + s]);
    float h[16];
#pragma unroll
    for (int s = 0; s < 16; s++) h[s] = 0.f;
    for (int c = 0; c < 8; c++) {
        size_t o = (size_t)(b * 8 + c) * 1024 + d;
#pragma unroll
        for (int s = 0; s < 16; s++) hstart[o * 16 + s] = h[s];
        float sc = Sc[o];
#pragma unroll
        for (int s = 0; s < 16; s++)
            h[s] = __expf(sc * Aa[s]) * h[s] + hend[o * 16 + s];
    }
}

__global__ __launch_bounds__(256) void scan3_k(
    const float* __restrict__ dt,
    const unsigned short* __restrict__ u,
    const unsigned short* __restrict__ uz,     // z at col 1024+d
    const unsigned short* __restrict__ proj,   // B at 32..47, C at 48..63
    const float* __restrict__ A_log,
    const float* __restrict__ Dp,
    const float* __restrict__ hstart,
    unsigned short* __restrict__ yg) {
    const int dg = blockIdx.x, c = blockIdx.y, b = blockIdx.z;
    const int d = dg * 256 + threadIdx.x;
    const size_t base = (size_t)b * 256 + c * 32;
    __shared__ float BCs[32][32];
    for (int i = threadIdx.x; i < 1024; i += 256) {
        int r = i >> 5, s = i & 31;
        BCs[r][s] = b2f(proj[(base + r) * 64 + 32 + s]);
    }
    __syncthreads();
    float Aa[16];
#pragma unroll
    for (int s = 0; s < 16; s++) Aa[s] = -__expf(A_log[d * 16 + s]);
    const float Dd = Dp[d];
    float h[16];
    size_t ho = ((size_t)(b * 8 + c) * 1024 + d) * 16;
#pragma unroll
    for (int s = 0; s < 16; s++) h[s] = hstart[ho + s];
    for (int l = 0; l < 32; l++) {
        size_t row = base + l;
        float dtv = dt[(row << 10) + d];
        float uu  = b2f(u[(row << 10) + d]);
        float zz  = b2f(uz[(row << 11) + 1024 + d]);
        float du  = dtv * uu;
        float y = 0.f;
#pragma unroll
        for (int s = 0; s < 16; s++) {
            h[s] = __expf(dtv * Aa[s]) * h[s] + du * BCs[l][s];
            y = fmaf(h[s], BCs[l][16 + s], y);
        }
        y = fmaf(uu, Dd, y);
        yg[(row << 10) + d] = f2b(y * (zz * sigmoidf_(zz)));
    }
}

// ---------- layernorm ----------
template<int HRES, int OF32, int OBF>
__global__ __launch_bounds__(256) void ln_k(const float* __restrict__ xin,
                                            const float* __restrict__ resin,
                                            const float* __restrict__ g,
                                            const float* __restrict__ b,
                                            float* __restrict__ outf,
                                            unsigned short* __restrict__ outb) {
    const int row = blockIdx.x, tid = threadIdx.x;
    float2 v = ((const float2*)(xin + (size_t)row * 512))[tid];
    if (HRES) {
        float2 r2 = ((const float2*)(resin + (size_t)row * 512))[tid];
        v.x += r2.x; v.y += r2.y;
    }
    float s = v.x + v.y, q = v.x * v.x + v.y * v.y;
#pragma unroll
    for (int o = 32; o > 0; o >>= 1) { s += __shfl_xor(s, o); q += __shfl_xor(q, o); }
    __shared__ float sm[4], qm[4];
    const int lane = tid & 63, wv = tid >> 6;
    if (lane == 0) { sm[wv] = s; qm[wv] = q; }
    __syncthreads();
    s = sm[0] + sm[1] + sm[2] + sm[3];
    q = qm[0] + qm[1] + qm[2] + qm[3];
    const float mu = s * (1.f / 512.f);
    const float ri = rsqrtf(q * (1.f / 512.f) - mu * mu + 1e-5f);
    float2 gg = ((const float2*)g)[tid];
    float2 bb = ((const float2*)b)[tid];
    float o0 = (v.x - mu) * ri * gg.x + bb.x;
    float o1 = (v.y - mu) * ri * gg.y + bb.y;
    if (OF32) ((float2*)(outf + (size_t)row * 512))[tid] = make_float2(o0, o1);
    if (OBF) {
        unsigned short* ob = outb + (size_t)row * 512 + tid * 2;
        ob[0] = f2b(o0); ob[1] = f2b(o1);
    }
}

// ---------- fused double layernorm: x2 = LN_s(mout); h = LN_f(x2) ----------
__global__ __launch_bounds__(256) void lnln_k(const float* __restrict__ xin,
                                              const float* __restrict__ g1,
                                              const float* __restrict__ b1,
                                              const float* __restrict__ g2,
                                              const float* __restrict__ b2,
                                              float* __restrict__ x2out,
                                              unsigned short* __restrict__ hout) {
    const int row = blockIdx.x, tid = threadIdx.x;
    const int lane = tid & 63, wv = tid >> 6;
    __shared__ float sm[4], qm[4];

    float2 v = ((const float2*)(xin + (size_t)row * 512))[tid];
    float s = v.x + v.y, q = v.x * v.x + v.y * v.y;
#pragma unroll
    for (int o = 32; o > 0; o >>= 1) { s += __shfl_xor(s, o); q += __shfl_xor(q, o); }
    if (lane == 0) { sm[wv] = s; qm[wv] = q; }
    __syncthreads();
    s = sm[0] + sm[1] + sm[2] + sm[3];
    q = qm[0] + qm[1] + qm[2] + qm[3];
    float mu = s * (1.f / 512.f);
    float ri = rsqrtf(q * (1.f / 512.f) - mu * mu + 1e-5f);
    float2 gg = ((const float2*)g1)[tid];
    float2 bb = ((const float2*)b1)[tid];
    float o0 = (v.x - mu) * ri * gg.x + bb.x;
    float o1 = (v.y - mu) * ri * gg.y + bb.y;
    ((float2*)(x2out + (size_t)row * 512))[tid] = make_float2(o0, o1);

    // second LN over (o0,o1)
    __syncthreads();
    s = o0 + o1; q = o0 * o0 + o1 * o1;
#pragma unroll
    for (int o = 32; o > 0; o >>= 1) { s += __shfl_xor(s, o); q += __shfl_xor(q, o); }
    if (lane == 0) { sm[wv] = s; qm[wv] = q; }
    __syncthreads();
    s = sm[0] + sm[1] + sm[2] + sm[3];
    q = qm[0] + qm[1] + qm[2] + qm[3];
    mu = s * (1.f / 512.f);
    ri = rsqrtf(q * (1.f / 512.f) - mu * mu + 1e-5f);
    gg = ((const float2*)g2)[tid];
    bb = ((const float2*)b2)[tid];
    float h0 = (o0 - mu) * ri * gg.x + bb.x;
    float h1 = (o1 - mu) * ri * gg.y + bb.y;
    unsigned short* ob = hout + (size_t)row * 512 + tid * 2;
    ob[0] = f2b(h0); ob[1] = f2b(h1);
}

// ---------- per-batch transpose x1 (b,l,d) f32 -> (b,d,l) bf16 ----------
__global__ __launch_bounds__(256) void trans_k(const float* __restrict__ x1,
                                               unsigned short* __restrict__ xt) {
    __shared__ float tile[32][33];
    const int b = blockIdx.z;
    const int d0 = blockIdx.x * 32, l0 = blockIdx.y * 32;
    const int c = threadIdx.x & 31, r = threadIdx.x >> 5;
    const float* src = x1 + ((size_t)b * 256 + l0) * 512 + d0;
#pragma unroll
    for (int i = 0; i < 4; i++) tile[r + i * 8][c] = src[(size_t)(r + i * 8) * 512 + c];
    __syncthreads();
    unsigned short* dst = xt + ((size_t)b * 512 + d0) * 256 + l0;
#pragma unroll
    for (int i = 0; i < 4; i++) dst[(size_t)(r + i * 8) * 256 + c] = f2b(tile[c][r + i * 8]);
}

// ---------- workspace layout (bytes) ----------
constexpr size_t OFF_WT_DIN  = 0;
constexpr size_t OFF_WT_SIN  = OFF_WT_DIN  + 2048ull * 512 * 2;
constexpr size_t OFF_WT_DOUT = OFF_WT_SIN  + 2048ull * 512 * 2;
constexpr size_t OFF_WT_SOUT = OFF_WT_DOUT + 512ull * 1024 * 2;
constexpr size_t OFF_WT_F1   = OFF_WT_SOUT + 512ull * 1024 * 2;
constexpr size_t OFF_WT_F2   = OFF_WT_F1   + 2048ull * 512 * 2;
constexpr size_t OFF_XPT_D   = OFF_WT_F2   + 512ull * 2048 * 2;   // xproj^T (64,1024) bf16
constexpr size_t OFF_XPT_S   = OFF_XPT_D   + 64ull * 1024 * 2;
constexpr size_t OFF_DTT_D   = OFF_XPT_S   + 64ull * 1024 * 2;    // dtw^T (1024,32) bf16
constexpr size_t OFF_DTT_S   = OFF_DTT_D   + 1024ull * 32 * 2;
constexpr size_t OFF_ACT     = OFF_DTT_S   + 1024ull * 32 * 2;    // xd / xg bf16 (8192x512)
constexpr size_t OFF_UZ      = OFF_ACT  + 8192ull * 512 * 2;      // uz bf16 (8192x2048); reused FFN mid
constexpr size_t OFF_U       = OFF_UZ   + 8192ull * 2048 * 2;     // u bf16 (8192x1024); reused h bf16
constexpr size_t OFF_PROJ    = OFF_U    + 8192ull * 1024 * 2;     // proj bf16 (8192x64)
constexpr size_t OFF_YG      = OFF_PROJ + 8192ull * 64 * 2;       // gated y bf16 (8192x1024)
constexpr size_t OFF_MOUT    = OFF_YG   + 8192ull * 1024 * 2;     // mamba out f32; reused as hend
constexpr size_t OFF_X1      = OFF_MOUT + 8192ull * 512 * 4;      // x1 f32
constexpr size_t OFF_X2      = OFF_X1   + 8192ull * 512 * 4;      // x2 f32
constexpr size_t OFF_X1T     = OFF_X2   + 8192ull * 512 * 4;      // x1^T bf16 (32,512,256)
constexpr size_t OFF_ADJB    = OFF_X1T  + 32ull * 512 * 256 * 2;  // adj bf16 (256x256)
constexpr size_t OFF_DT      = OFF_ADJB + 256ull * 256 * 2;       // dt f32 (32MB) / xpp f32 partials (16MB)
constexpr size_t OFF_HST     = OFF_DT   + 8192ull * 1024 * 4;     // hstart (32,8,1024,16) f32
constexpr size_t OFF_SC      = OFF_HST  + 32ull * 8 * 1024 * 16 * 4; // Sc (32,8,1024) f32

extern "C" void kernel_launch(void* const* d_in, const int* in_sizes, int n_in,
                              void* d_out, int out_size, void* d_ws, size_t ws_size,
                              hipStream_t stream) {
    (void)in_sizes; (void)n_in; (void)out_size; (void)ws_size;
    const float* x      = (const float*)d_in[0];
    const float* dinw   = (const float*)d_in[1];
    const float* dconvw = (const float*)d_in[2];
    const float* dconvb = (const float*)d_in[3];
    const float* dxproj = (const float*)d_in[4];
    const float* ddtw   = (const float*)d_in[5];
    const float* ddtb   = (const float*)d_in[6];
    const float* dAlog  = (const float*)d_in[7];
    const float* dD     = (const float*)d_in[8];
    const float* doutw  = (const float*)d_in[9];
    const float* dlng   = (const float*)d_in[10];
    const float* dlnb   = (const float*)d_in[11];
    const float* sinw   = (const float*)d_in[12];
    const float* sconvw = (const float*)d_in[13];
    const float* sconvb = (const float*)d_in[14];
    const float* sxproj = (const float*)d_in[15];
    const float* sdtw   = (const float*)d_in[16];
    const float* sdtb   = (const float*)d_in[17];
    const float* sAlog  = (const float*)d_in[18];
    const float* sD     = (const float*)d_in[19];
    const float* soutw  = (const float*)d_in[20];
    const float* slng   = (const float*)d_in[21];
    const float* slnb   = (const float*)d_in[22];
    const float* semb1  = (const float*)d_in[23];
    const float* semb2  = (const float*)d_in[24];
    const float* flng   = (const float*)d_in[25];
    const float* flnb   = (const float*)d_in[26];
    const float* fw1    = (const float*)d_in[27];
    const float* fb1    = (const float*)d_in[28];
    const float* fw2    = (const float*)d_in[29];
    const float* fb2    = (const float*)d_in[30];

    char* ws = (char*)d_ws;
    unsigned short* wtDin  = (unsigned short*)(ws + OFF_WT_DIN);
    unsigned short* wtSin  = (unsigned short*)(ws + OFF_WT_SIN);
    unsigned short* wtDout = (unsigned short*)(ws + OFF_WT_DOUT);
    unsigned short* wtSout = (unsigned short*)(ws + OFF_WT_SOUT);
    unsigned short* wtF1   = (unsigned short*)(ws + OFF_WT_F1);
    unsigned short* wtF2   = (unsigned short*)(ws + OFF_WT_F2);
    unsigned short* xptD   = (unsigned short*)(ws + OFF_XPT_D);
    unsigned short* xptS   = (unsigned short*)(ws + OFF_XPT_S);
    unsigned short* dttD   = (unsigned short*)(ws + OFF_DTT_D);
    unsigned short* dttS   = (unsigned short*)(ws + OFF_DTT_S);
    unsigned short* actIn  = (unsigned short*)(ws + OFF_ACT);
    unsigned short* uzBuf  = (unsigned short*)(ws + OFF_UZ);
    unsigned short* uBuf   = (unsigned short*)(ws + OFF_U);
    unsigned short* projB  = (unsigned short*)(ws + OFF_PROJ);
    unsigned short* ygBuf  = (unsigned short*)(ws + OFF_YG);
    float*          moutB  = (float*)(ws + OFF_MOUT);
    float*          hendB  = moutB;                        // reuse (dead until out-GEMM)
    float*          x1Buf  = (float*)(ws + OFF_X1);
    float*          x2Buf  = (float*)(ws + OFF_X2);
    unsigned short* x1tBuf = (unsigned short*)(ws + OFF_X1T);
    unsigned short* adjB   = (unsigned short*)(ws + OFF_ADJB);
    float*          dtBuf  = (float*)(ws + OFF_DT);
    float*          xppBuf = dtBuf;   // xproj split-K partials (16MB); dead before dt-GEMM writes
    float*          hstB   = (float*)(ws + OFF_HST);
    float*          scB    = (float*)(ws + OFF_SC);
    unsigned short* hBuf   = uBuf;    // reuse (u dead after scan)
    unsigned short* midBuf = uzBuf;   // reuse (uz dead after scan)

    float* outX   = (float*)d_out;
    float* outAdj = outX + 4194304;

    // 1) weight transposes/converts
    WtArgs wa;
    wa.m[0]  = WtDesc{dinw,   wtDin,  512,  2048, 0};
    wa.m[1]  = WtDesc{sinw,   wtSin,  512,  2048, 1024};
    wa.m[2]  = WtDesc{doutw,  wtDout, 1024, 512,  2048};
    wa.m[3]  = WtDesc{soutw,  wtSout, 1024, 512,  2560};
    wa.m[4]  = WtDesc{fw1,    wtF1,   512,  2048, 3072};
    wa.m[5]  = WtDesc{fw2,    wtF2,   2048, 512,  4096};
    wa.m[6]  = WtDesc{dxproj, xptD,   1024, 64,   5120};
    wa.m[7]  = WtDesc{sxproj, xptS,   1024, 64,   5184};
    wa.m[8]  = WtDesc{ddtw,   dttD,   32,   1024, 5248};
    wa.m[9]  = WtDesc{sdtw,   dttS,   32,   1024, 5280};
    wa.m[10] = WtDesc{dinw,   wtDin,  512,  2048, 0x7fffffff};
    wa.m[11] = WtDesc{dinw,   wtDin,  512,  2048, 0x7fffffff};
    wtrans_k<<<dim3(5312), dim3(256), 0, stream>>>(wa);

    diff_k<<<dim3(4096), dim3(256), 0, stream>>>(x, actIn);
    adj_k<<<dim3(256), dim3(256), 0, stream>>>(semb1, semb2, outAdj, adjB);

    // ---- stage 1: DiffSSM mamba ----
    gemm256_k<0,0><<<dim3(32,8), dim3(512), 0, stream>>>(
        actIn, wtDin, uzBuf, nullptr, 8192, 2048, 512, 512);
    conv_k<<<dim3(1024), dim3(256), 0, stream>>>(uzBuf, dconvw, dconvb, uBuf);
    // xproj: split-K x8 (each part K=128, 2 iters), f32 partials -> reduce to bf16
    gemm_k<64,64,64,2,2,2, 0,0,0,0,0><<<dim3(128,1,8), dim3(256), 0, stream>>>(
        uBuf, xptD, xppBuf, nullptr, nullptr, 8192, 64, 128, 1024, 1024, 128, 128, 524288);
    xred_k<<<dim3(512), dim3(256), 0, stream>>>(xppBuf, projB);
    // dt = softplus(proj[:,0:32] @ dtw^T + dtb), f32 out (r12-proven)
    gemm_k<128,128,32,2,4,4, 0,1,0,0,1><<<dim3(64,8,1), dim3(256), 0, stream>>>(
        projB, dttD, dtBuf, ddtb, nullptr, 8192, 1024, 32, 64, 32, 0, 0, 0);
    scan1_k<<<dim3(4,8,32), dim3(256), 0, stream>>>(dtBuf, uBuf, projB, dAlog, hendB, scB);
    scan2_k<<<dim3(4,32),   dim3(256), 0, stream>>>(hendB, scB, dAlog, hstB);
    scan3_k<<<dim3(4,8,32), dim3(256), 0, stream>>>(dtBuf, uBuf, uzBuf, projB, dAlog, dD, hstB, ygBuf);
    // out-GEMM with fused residual (+x), f32 out
    gemm_k<128,128,64,2,4,4, 0,0,0,1,0><<<dim3(64,4,1), dim3(256), 0, stream>>>(
        ygBuf, wtDout, moutB, nullptr, x, 8192, 512, 1024, 1024, 1024, 0, 0, 0);
    ln_k<0,1,0><<<dim3(8192), dim3(256), 0, stream>>>(moutB, nullptr, dlng, dlnb, x1Buf, nullptr);

    // ---- stage 2: SpatialGraphMamba ----
    trans_k<<<dim3(16,8,32), dim3(256), 0, stream>>>(x1Buf, x1tBuf);
    gemm_k<128,128,64,2,4,4, 1,0,0,0,0><<<dim3(2,4,32), dim3(256), 0, stream>>>(
        adjB, x1tBuf, actIn, nullptr, nullptr, 256, 512, 256, 256, 256, 0, 131072, 131072);
    gemm256_k<0,0><<<dim3(32,8), dim3(512), 0, stream>>>(
        actIn, wtSin, uzBuf, nullptr, 8192, 2048, 512, 512);
    conv_k<<<dim3(1024), dim3(256), 0, stream>>>(uzBuf, sconvw, sconvb, uBuf);
    gemm_k<64,64,64,2,2,2, 0,0,0,0,0><<<dim3(128,1,8), dim3(256), 0, stream>>>(
        uBuf, xptS, xppBuf, nullptr, nullptr, 8192, 64, 128, 1024, 1024, 128, 128, 524288);
    xred_k<<<dim3(512), dim3(256), 0, stream>>>(xppBuf, projB);
    gemm_k<128,128,32,2,4,4, 0,1,0,0,1><<<dim3(64,8,1), dim3(256), 0, stream>>>(
        projB, dttS, dtBuf, sdtb, nullptr, 8192, 1024, 32, 64, 32, 0, 0, 0);
    scan1_k<<<dim3(4,8,32), dim3(256), 0, stream>>>(dtBuf, uBuf, projB, sAlog, hendB, scB);
    scan2_k<<<dim3(4,32),   dim3(256), 0, stream>>>(hendB, scB, sAlog, hstB);
    scan3_k<<<dim3(4,8,32), dim3(256), 0, stream>>>(dtBuf, uBuf, uzBuf, projB, sAlog, sD, hstB, ygBuf);
    gemm_k<128,128,64,2,4,4, 0,0,0,1,0><<<dim3(64,4,1), dim3(256), 0, stream>>>(
        ygBuf, wtSout, moutB, nullptr, x1Buf, 8192, 512, 1024, 1024, 1024, 0, 0, 0);
    // fused: x2 = LN_s(mout); h = LN_f(x2)
    lnln_k<<<dim3(8192), dim3(256), 0, stream>>>(moutB, slng, slnb, flng, flnb, x2Buf, hBuf);

    // ---- stage 3: FFN ----
    gemm256_k<1,1><<<dim3(32,8), dim3(512), 0, stream>>>(
        hBuf, wtF1, midBuf, fb1, 8192, 2048, 512, 512);
    gemm_k<128,128,64,2,4,4, 0,1,0,1,0><<<dim3(64,4,1), dim3(256), 0, stream>>>(
        midBuf, wtF2, outX, fb2, x2Buf, 8192, 512, 2048, 2048, 2048, 0, 0, 0);
}